// Round 13
// baseline (2154.439 us; speedup 1.0000x reference)
//
#include <hip/hip_runtime.h>
#include <cstdint>
#include <cstddef>

constexpr int N_NODES = 65536;
constexpr int D       = 128;
constexpr int E_EDGES = 524288;
constexpr int LVLS    = 8;
constexpr int EL      = E_EDGES / LVLS;   // 65536
constexpr int OSTR    = 65540;            // offs segment stride (16B-aligned)

typedef unsigned int  u32;
typedef unsigned short u16;
typedef __attribute__((ext_vector_type(8)))  short short8;   // 8 bf16 (4 VGPR)
typedef __attribute__((ext_vector_type(16))) float f32x16;

__device__ __forceinline__ float sigmoidf_(float x) { return 1.0f / (1.0f + expf(-x)); }

__device__ __forceinline__ u32 bf_hi(float f) {           // f32 -> bf16 bits (RNE)
    u32 x = __float_as_uint(f);
    return (x + 0x7fffu + ((x >> 16) & 1u)) >> 16;
}
__device__ __forceinline__ float bf_f(u32 hbits) { return __uint_as_float(hbits << 16); }

// Swizzled byte offset inside a [rows][32 bf16] LDS tile (64B rows).
// XOR bits 4-5: bijective 16B-slot permute within each 64B row.
__device__ __forceinline__ int swz(int row, int kbyte) {
    return row * 64 + (kbyte ^ ((row & 3) << 4));
}

// wave-level async global->LDS DMA: 64 lanes x 16B. LDS dest wave-uniform
// (HW adds lane*16); global src is PER-LANE -> swizzle folded into src addr.
__device__ __forceinline__ void gload_lds16(const void* g, void* l) {
    __builtin_amdgcn_global_load_lds(
        (const __attribute__((address_space(1))) unsigned int*)g,
        (__attribute__((address_space(3))) unsigned int*)l, 16, 0, 0);
}

__device__ __forceinline__ float wave_sum(float v) {
#pragma unroll
    for (int off = 32; off > 0; off >>= 1) v += __shfl_down(v, off, 64);
    return v;
}

// ---------------------------------------------------------------------------
__global__ __launch_bounds__(256)
void prep_kernel(const float* __restrict__ We_f, const float* __restrict__ Wa_f,
                 const float* __restrict__ be_f, const float* __restrict__ ba_f,
                 const float* __restrict__ We_b, const float* __restrict__ Wa_b,
                 const float* __restrict__ be_b, const float* __restrict__ ba_b,
                 float* __restrict__ u_f, float* __restrict__ u_b, float* __restrict__ cst)
{
    int t = threadIdx.x;
    if (t < 128) {
        float s = 0.f;
        for (int d = 0; d < 128; ++d) s = fmaf(We_f[d * 128 + t], Wa_f[128 + d], s);
        u_f[t] = s;
    } else {
        int c = t - 128;
        float s = 0.f;
        for (int d = 0; d < 128; ++d) s = fmaf(We_b[d * 128 + c], Wa_b[128 + d], s);
        u_b[c] = s;
    }
    if (t == 0) {
        float s = 0.f;
        for (int d = 0; d < 128; ++d) s = fmaf(be_f[d], Wa_f[128 + d], s);
        cst[0] = s + ba_f[0];
    }
    if (t == 255) {
        float s = 0.f;
        for (int d = 0; d < 128; ++d) s = fmaf(be_b[d], Wa_b[128 + d], s);
        cst[1] = s + ba_b[0];
    }
}

// ---------------------------------------------------------------------------
// weights -> LINEAR bf16 split: hi[m][384][128], lo[m][128][128] (rows 256..383)
__global__ __launch_bounds__(256)
void convert_w(const float* __restrict__ W0, const float* __restrict__ W1,
               const float* __restrict__ W2, const float* __restrict__ W3,
               u16* __restrict__ hi4, u16* __restrict__ lo4)
{
    const float* Ws[4] = {W0, W1, W2, W3};
    int m = blockIdx.y;
    int i = blockIdx.x * 256 + threadIdx.x;        // < 49152 ; i = rw*128 + k
    int rw = i >> 7, k = i & 127;
    float v = Ws[m][i];
    u32 hb = bf_hi(v);
    hi4[(size_t)m * 49152 + i] = (u16)hb;
    if (rw >= 256)
        lo4[(size_t)m * 16384 + (size_t)(rw - 256) * 128 + k] = (u16)bf_hi(v - bf_f(hb));
}

// ---------------------------------------------------------------------------
// x -> linear bf16 split images (256B/row each)
__global__ __launch_bounds__(256)
void convert_x(const float* __restrict__ x, unsigned char* __restrict__ xhi,
               unsigned char* __restrict__ xlo)
{
    int idx = blockIdx.x * 256 + threadIdx.x;      // < 65536*64
    int n = idx >> 6, d = (idx & 63) << 1;
    float2 v = *reinterpret_cast<const float2*>(x + (size_t)n * 128 + d);
    u32 h0 = bf_hi(v.x), h1 = bf_hi(v.y);
    u32 l0 = bf_hi(v.x - bf_f(h0)), l1 = bf_hi(v.y - bf_f(h1));
    size_t off = (size_t)n * 256 + (size_t)d * 2;
    *reinterpret_cast<u32*>(xhi + off) = h0 | (h1 << 16);
    *reinterpret_cast<u32*>(xlo + off) = l0 | (l1 << 16);
}

// ---------------------------------------------------------------------------
__global__ __launch_bounds__(256)
void edot_kernel(const float* __restrict__ ea, const float* __restrict__ u_f,
                 const float* __restrict__ u_b, const float* __restrict__ cst,
                 float* __restrict__ edot_f, float* __restrict__ edot_b)
{
    int wv = threadIdx.x >> 6, lane = threadIdx.x & 63;
    int e = blockIdx.x * 4 + wv;
    if (e >= E_EDGES) return;
    int d = lane << 1;
    float2 v  = *reinterpret_cast<const float2*>(ea + (size_t)e * 128 + d);
    float2 uf = *reinterpret_cast<const float2*>(u_f + d);
    float2 ub = *reinterpret_cast<const float2*>(u_b + d);
    float af = wave_sum(v.x * uf.x + v.y * uf.y);
    float ab = wave_sum(v.x * ub.x + v.y * ub.y);
    if (lane == 0) {
        edot_f[e] = af + cst[0];
        edot_b[e] = ab + cst[1];
    }
}

// ---------------------------------------------------------------------------
__global__ __launch_bounds__(256)
void count_flags(const int* __restrict__ ei, int* __restrict__ counts,
                 int* __restrict__ flag_f, int* __restrict__ flag_b)
{
    int e = blockIdx.x * 256 + threadIdx.x;
    int lv = e >> 16;
    int s = ei[e], t = ei[E_EDGES + e];
    atomicAdd(&counts[(size_t)lv * 65536 + t], 1);           // fwd: target = dst
    atomicAdd(&counts[(size_t)(8 + lv) * 65536 + s], 1);     // bwd: target = src
    flag_f[t] = 1;
    flag_b[s] = 1;
}

// ---------------------------------------------------------------------------
__global__ __launch_bounds__(1024)
void scan_compact(const int* __restrict__ counts, int* __restrict__ offs,
                  int* __restrict__ rows, int* __restrict__ cnts)
{
    __shared__ int sbuf[1024];
    __shared__ int nbuf[1024];
    int dl = blockIdx.x;
    const int4* c4 = reinterpret_cast<const int4*>(counts + (size_t)dl * 65536);
    int* o = offs + (size_t)dl * OSTR;
    int* rw = rows + (size_t)dl * 65536;
    int t = threadIdx.x;
    int cv[64];
#pragma unroll 4
    for (int k4 = 0; k4 < 16; ++k4) {
        int4 v = c4[t * 16 + k4];
        cv[k4 * 4 + 0] = v.x; cv[k4 * 4 + 1] = v.y;
        cv[k4 * 4 + 2] = v.z; cv[k4 * 4 + 3] = v.w;
    }
    int s = 0, nz = 0;
#pragma unroll
    for (int k = 0; k < 64; ++k) { s += cv[k]; nz += (cv[k] > 0); }
    sbuf[t] = s;
    nbuf[t] = nz;
    __syncthreads();
    int val = s, nval = nz;
    for (int off = 1; off < 1024; off <<= 1) {
        int add  = (t >= off) ? sbuf[t - off] : 0;
        int nadd = (t >= off) ? nbuf[t - off] : 0;
        __syncthreads();
        val += add;
        nval += nadd;
        sbuf[t] = val;
        nbuf[t] = nval;
        __syncthreads();
    }
    int run  = val - s;
    int nrun = nval - nz;
    int base = t * 64;
    int4* o4 = reinterpret_cast<int4*>(o + base);
#pragma unroll 4
    for (int k4 = 0; k4 < 16; ++k4) {
        int4 ov;
        ov.x = run; run += cv[k4 * 4 + 0];
        ov.y = run; run += cv[k4 * 4 + 1];
        ov.z = run; run += cv[k4 * 4 + 2];
        ov.w = run; run += cv[k4 * 4 + 3];
        o4[k4] = ov;
#pragma unroll
        for (int q = 0; q < 4; ++q)
            if (cv[k4 * 4 + q] > 0) rw[nrun++] = base + k4 * 4 + q;
    }
    if (t == 1023) { o[65536] = val; cnts[dl] = nval; }
}

// ---------------------------------------------------------------------------
__global__ __launch_bounds__(256)
void fill_csr(const int* __restrict__ ei, const float* __restrict__ edot_f,
              const float* __restrict__ edot_b, const int* __restrict__ offs,
              int* __restrict__ cursor, int2* __restrict__ csr)
{
    int idx = blockIdx.x * 256 + threadIdx.x;       // < 2E
    int dir = idx >= E_EDGES;
    int ge = dir ? idx - E_EDGES : idx;
    int lv = ge >> 16;
    int dl = dir * 8 + lv;
    int i = dir ? ei[ge] : ei[E_EDGES + ge];
    int j = dir ? ei[E_EDGES + ge] : ei[ge];
    int pos = offs[(size_t)dl * OSTR + i] + atomicAdd(&cursor[(size_t)dl * 65536 + i], 1);
    int2 v;
    v.x = j;
    v.y = __float_as_int(dir ? edot_b[ge] : edot_f[ge]);
    csr[(size_t)dl * EL + pos] = v;
}

// ---------------------------------------------------------------------------
// qdot for all nodes; exact-f32 GRU for roots (writes h f32 + split images).
__global__ __launch_bounds__(256)
void root_init(const float* __restrict__ hp, const int* __restrict__ flag,
               const float* __restrict__ Wi, const float* __restrict__ bi,
               const float* __restrict__ bh, const float* __restrict__ wa,
               float* __restrict__ h, unsigned char* __restrict__ h_hi,
               unsigned char* __restrict__ h_lo, int write_img,
               float* __restrict__ qdot, float* __restrict__ hdot)
{
    int wv = threadIdx.x >> 6, lane = threadIdx.x & 63;
    int n = blockIdx.x * 4 + wv;
    int d = lane << 1;
    const float* hprow = hp + (size_t)n * 128;
    float2 hpv = *reinterpret_cast<const float2*>(hprow + d);
    float qd = wave_sum(hpv.x * wa[d] + hpv.y * wa[d + 1]);
    if (lane == 0) qdot[n] = qd;
    bool root = (flag[n] == 0);
    float hv[2] = {0.f, 0.f};
    if (root) {   // rare; exact f32 path
#pragma unroll
        for (int q = 0; q < 2; ++q) {
            int dd = d + q;
            float g0 = bi[dd], g1 = bi[dd + 128], g2 = bi[dd + 256];
            for (int k = 0; k < 128; ++k) {
                float a = hprow[k];
                g0 = fmaf(a, Wi[(size_t)dd * 128 + k], g0);
                g1 = fmaf(a, Wi[(size_t)(dd + 128) * 128 + k], g1);
                g2 = fmaf(a, Wi[(size_t)(dd + 256) * 128 + k], g2);
            }
            float rr = sigmoidf_(g0 + bh[dd]);
            float zz = sigmoidf_(g1 + bh[dd + 128]);
            float nn = tanhf(g2 + rr * bh[dd + 256]);
            hv[q] = (1.f - zz) * nn;            // hidden = 0 for roots
        }
        *reinterpret_cast<float2*>(h + (size_t)n * 128 + d) = make_float2(hv[0], hv[1]);
        if (write_img) {
            u32 hb0 = bf_hi(hv[0]), hb1 = bf_hi(hv[1]);
            u32 lb0 = bf_hi(hv[0] - bf_f(hb0)), lb1 = bf_hi(hv[1] - bf_f(hb1));
            size_t off = (size_t)n * 256 + (size_t)d * 2;
            *reinterpret_cast<u32*>(h_hi + off) = hb0 | (hb1 << 16);
            *reinterpret_cast<u32*>(h_lo + off) = lb0 | (lb1 << 16);
        }
    }
    float hd = wave_sum(hv[0] * wa[128 + d] + hv[1] * wa[128 + d + 1]);
    if (lane == 0) hdot[n] = root ? hd : 0.f;
}

// ---------------------------------------------------------------------------
// FUSED per-level kernel: attention (own 128 target rows -> LDS A-tile as
// bf16 hi/lo, swizzled) + dual-phase GEMM (msg@Wh then hp@Wi) + GRU epilogue.
// Writes h_stage (compacted, coalesced) + hdot_stage; commit_kernel scatters.
// Reads live h/hdot (stable: epilogue never writes them -> no intra-level race).
__global__ __launch_bounds__(512, 1)
void level_kernel(const int* __restrict__ pcnt, const int* __restrict__ rows,
                  const int* __restrict__ offs, const int2* __restrict__ csr,
                  const float* __restrict__ qdot, const float* __restrict__ hdot,
                  const float* __restrict__ hsrc,
                  const unsigned char* __restrict__ hp_hi, const unsigned char* __restrict__ hp_lo,
                  const u16* __restrict__ Whhi, const u16* __restrict__ Whlo,
                  const u16* __restrict__ Wihi, const u16* __restrict__ Wilo,
                  const float* __restrict__ bi, const float* __restrict__ bh,
                  const float* __restrict__ wa,
                  float* __restrict__ h_stage, float* __restrict__ hdot_stage,
                  unsigned char* __restrict__ h_hi, unsigned char* __restrict__ h_lo,
                  int write_img)
{
    // LDS: As 64KB (msg tile: hi[4ks x 8KB] @0, lo @32768; phase-B recycles
    // bytes 0..32767 as 2x16KB hp staging) | Bs 2x32KB | red 2KB | rows 512B
    __shared__ __align__(16) unsigned char smem[65536 + 65536 + 2048 + 512];
    unsigned char* As = smem;
    unsigned char* Bs = smem + 65536;
    float* red   = (float*)(smem + 131072);
    int* rowsLds = (int*)(smem + 131072 + 2048);

    const int tid = threadIdx.x;
    const int cnt = *pcnt;
    const int row0 = blockIdx.x * 128;
    if (row0 >= cnt) return;

    const int lane = tid & 63, wv = tid >> 6;
    const int q = wv & 3, mh = wv >> 2;
    const int l31 = lane & 31, l5 = lane >> 5;

    if (tid < 128) {
        int gr = row0 + tid;
        rowsLds[tid] = (gr < cnt) ? rows[gr] : 0;
    }

    // B-source per-lane offsets (swizzle folded into source; LDS dest linear)
    size_t bsrc[3];
#pragma unroll
    for (int k = 0; k < 3; ++k) {
        int rwB = wv * 48 + k * 16 + (lane >> 2);             // rows 0..383
        bsrc[k] = (size_t)rwB * 256 + (((lane & 3) << 4) ^ ((rwB & 3) << 4));
    }
    const int rwL = wv * 16 + (lane >> 2);                     // lo rows 0..127
    const size_t lsrc = (size_t)rwL * 256 + (((lane & 3) << 4) ^ ((rwL & 3) << 4));
    const int rwA = wv * 16 + (lane >> 2);
    const int slA = ((lane & 3) << 4) ^ ((rwA & 3) << 4);

    // prefetch tile-0 weights (Wh, ks=0) while attention runs
    {
        unsigned char* Bd = Bs;   // buf 0
#pragma unroll
        for (int k = 0; k < 3; ++k)
            gload_lds16((const unsigned char*)Whhi + bsrc[k], Bd + (wv * 3 + k) * 1024);
        gload_lds16((const unsigned char*)Whlo + lsrc, Bd + 24576 + wv * 1024);
    }

    __syncthreads();   // rowsLds visible
    const size_t baseA1 = (size_t)rowsLds[rwA] * 256 + slA;    // gathered hp rows

    // ---- attention: 16 half-waves x 8 rows -> As msg tile (bf16 hi/lo)
    {
        int hw = tid >> 5;
        int d0 = l31 << 2;
        int ks = l31 >> 3;
        int kb = (l31 & 7) << 3;
        for (int k = 0; k < 8; ++k) {
            int rl = hw + 16 * k;
            int i = rowsLds[rl];
            int o0 = offs[i], o1 = offs[i + 1];
            float qi = qdot[i];
            float den = 0.f;
            float4 acc4 = make_float4(0.f, 0.f, 0.f, 0.f);
            for (int e = o0; e < o1; ++e) {
                int2 je = csr[e];
                float ex = expf(qi + hdot[je.x] + __int_as_float(je.y));
                float4 hv = *reinterpret_cast<const float4*>(hsrc + (size_t)je.x * 128 + d0);
                den += ex;
                acc4.x = fmaf(ex, hv.x, acc4.x);
                acc4.y = fmaf(ex, hv.y, acc4.y);
                acc4.z = fmaf(ex, hv.z, acc4.z);
                acc4.w = fmaf(ex, hv.w, acc4.w);
            }
            float inv = 1.f / den;
            float m0 = acc4.x * inv, m1 = acc4.y * inv;
            float m2 = acc4.z * inv, m3 = acc4.w * inv;
            u32 h0 = bf_hi(m0), h1 = bf_hi(m1), h2 = bf_hi(m2), h3 = bf_hi(m3);
            u32 l0 = bf_hi(m0 - bf_f(h0)), l1 = bf_hi(m1 - bf_f(h1));
            u32 l2 = bf_hi(m2 - bf_f(h2)), l3 = bf_hi(m3 - bf_f(h3));
            int off = ks * 8192 + swz(rl, kb);
            *reinterpret_cast<uint2*>(As + off)         = make_uint2(h0 | (h1 << 16), h2 | (h3 << 16));
            *reinterpret_cast<uint2*>(As + 32768 + off) = make_uint2(l0 | (l1 << 16), l2 | (l3 << 16));
        }
    }
    __syncthreads();   // msg tile + tile-0 B resident (drains vmcnt too)

    // ---- extract epilogue msg values before phase-B staging recycles As
    float mval[2][16];
#pragma unroll
    for (int mt = 0; mt < 2; ++mt)
#pragma unroll
        for (int rg = 0; rg < 16; ++rg) {
            int rl = mh * 64 + mt * 32 + (rg & 3) + ((rg >> 2) << 3) + (l5 << 2);
            int off = q * 8192 + swz(rl, l31 * 2);
            u16 hb = *reinterpret_cast<const u16*>(As + off);
            u16 lb = *reinterpret_cast<const u16*>(As + 32768 + off);
            mval[mt][rg] = bf_f(hb) + bf_f(lb);
        }
    asm volatile("s_waitcnt lgkmcnt(0)");
    __builtin_amdgcn_sched_barrier(0);

    f32x16 acc[2][3];
#pragma unroll
    for (int mt = 0; mt < 2; ++mt)
#pragma unroll
        for (int g = 0; g < 3; ++g) acc[mt][g] = (f32x16)0.0f;
    f32x16 ghn[2];

    auto STAGE = [&](int tt) {
        int b = tt & 1;
        unsigned char* Bd = Bs + b * 32768;
        if (tt >= 4) {
            size_t ko = (size_t)(tt - 4) * 64;
            unsigned char* Ad = As + b * 16384 + wv * 1024;
            gload_lds16(hp_hi + baseA1 + ko, Ad);
            gload_lds16(hp_lo + baseA1 + ko, Ad + 8192);
#pragma unroll
            for (int k = 0; k < 3; ++k)
                gload_lds16((const unsigned char*)Wihi + bsrc[k] + ko, Bd + (wv * 3 + k) * 1024);
            gload_lds16((const unsigned char*)Wilo + lsrc + ko, Bd + 24576 + wv * 1024);
        } else {
            size_t ko = (size_t)tt * 64;
#pragma unroll
            for (int k = 0; k < 3; ++k)
                gload_lds16((const unsigned char*)Whhi + bsrc[k] + ko, Bd + (wv * 3 + k) * 1024);
            gload_lds16((const unsigned char*)Whlo + lsrc + ko, Bd + 24576 + wv * 1024);
        }
    };

    for (int t = 0; t < 8; ++t) {
        if (t < 7) STAGE(t + 1);
        __builtin_amdgcn_sched_barrier(0);
        if (t < 3)      asm volatile("s_waitcnt vmcnt(4)");   // next tile B-only in flight
        else if (t < 7) asm volatile("s_waitcnt vmcnt(6)");   // next tile A+B in flight
        else            asm volatile("s_waitcnt vmcnt(0)");
        __builtin_amdgcn_s_barrier();
        __builtin_amdgcn_sched_barrier(0);

        const unsigned char *a_hi, *a_lo;
        if (t < 4) { a_hi = As + t * 8192;          a_lo = As + 32768 + t * 8192; }
        else       { a_hi = As + (t & 1) * 16384;   a_lo = a_hi + 8192; }
        const unsigned char* Bb = Bs + (t & 1) * 32768;
#pragma unroll
        for (int kh = 0; kh < 2; ++kh) {
            short8 a[2][2];
#pragma unroll
            for (int mt = 0; mt < 2; ++mt) {
                a[mt][0] = *reinterpret_cast<const short8*>(
                    a_hi + swz(mh * 64 + mt * 32 + l31, kh * 32 + l5 * 16));
                a[mt][1] = *reinterpret_cast<const short8*>(
                    a_lo + swz(mh * 64 + mt * 32 + l31, kh * 32 + l5 * 16));
            }
            short8 b0 = *reinterpret_cast<const short8*>(
                Bb + swz(q * 32 + l31, kh * 32 + l5 * 16));
            short8 b1 = *reinterpret_cast<const short8*>(
                Bb + swz(q * 32 + 128 + l31, kh * 32 + l5 * 16));
            short8 b2 = *reinterpret_cast<const short8*>(
                Bb + swz(q * 32 + 256 + l31, kh * 32 + l5 * 16));
            short8 bl2 = *reinterpret_cast<const short8*>(
                Bb + 24576 + swz(q * 32 + l31, kh * 32 + l5 * 16));
#pragma unroll
            for (int mt = 0; mt < 2; ++mt) {
                acc[mt][0] = __builtin_amdgcn_mfma_f32_32x32x16_bf16(a[mt][0], b0, acc[mt][0], 0, 0, 0);
                acc[mt][0] = __builtin_amdgcn_mfma_f32_32x32x16_bf16(a[mt][1], b0, acc[mt][0], 0, 0, 0);
                acc[mt][1] = __builtin_amdgcn_mfma_f32_32x32x16_bf16(a[mt][0], b1, acc[mt][1], 0, 0, 0);
                acc[mt][1] = __builtin_amdgcn_mfma_f32_32x32x16_bf16(a[mt][1], b1, acc[mt][1], 0, 0, 0);
                acc[mt][2] = __builtin_amdgcn_mfma_f32_32x32x16_bf16(a[mt][0], b2, acc[mt][2], 0, 0, 0);
                acc[mt][2] = __builtin_amdgcn_mfma_f32_32x32x16_bf16(a[mt][0], bl2, acc[mt][2], 0, 0, 0);
                acc[mt][2] = __builtin_amdgcn_mfma_f32_32x32x16_bf16(a[mt][1], b2, acc[mt][2], 0, 0, 0);
            }
        }
        if (t == 3) {                        // end of phase A: stash gh_n
            ghn[0] = acc[0][2];
            ghn[1] = acc[1][2];
            acc[0][2] = (f32x16)0.0f;
            acc[1][2] = (f32x16)0.0f;
        }
        __builtin_amdgcn_s_barrier();        // reads done before buf reuse
        __builtin_amdgcn_sched_barrier(0);
    }

    // ---- epilogue
    const int d = q * 32 + l31;
    const float wa2d = wa[128 + d];
    const float bi0 = bi[d], bi1 = bi[d + 128], bi2 = bi[d + 256];
    const float bh0 = bh[d], bh1 = bh[d + 128], bh2 = bh[d + 256];

#pragma unroll
    for (int mt = 0; mt < 2; ++mt)
#pragma unroll
        for (int rg = 0; rg < 16; ++rg) {
            int rl = mh * 64 + mt * 32 + (rg & 3) + ((rg >> 2) << 3) + (l5 << 2);
            int gr = row0 + rl;
            bool ok = gr < cnt;
            int n = rowsLds[rl];
            float rr = sigmoidf_(acc[mt][0][rg] + bi0 + bh0);
            float zz = sigmoidf_(acc[mt][1][rg] + bi1 + bh1);
            float nn = tanhf(acc[mt][2][rg] + bi2 + rr * (ghn[mt][rg] + bh2));
            float hv = (1.f - zz) * nn + zz * mval[mt][rg];    // hidden = msg
            if (ok) {
                h_stage[(size_t)gr * 128 + d] = hv;            // compacted, coalesced
                if (write_img) {
                    u32 hb = bf_hi(hv);
                    *reinterpret_cast<u16*>(h_hi + (size_t)n * 256 + (size_t)d * 2) = (u16)hb;
                    *reinterpret_cast<u16*>(h_lo + (size_t)n * 256 + (size_t)d * 2) =
                        (u16)bf_hi(hv - bf_f(hb));
                }
            }
            float pd = hv * wa2d;
#pragma unroll
            for (int o = 1; o < 32; o <<= 1) pd += __shfl_xor(pd, o, 64);
            if (l31 == 0) red[rl * 4 + q] = pd;
        }
    __syncthreads();
    if (tid < 128 && row0 + tid < cnt)
        hdot_stage[row0 + tid] = red[tid * 4] + red[tid * 4 + 1] +
                                 red[tid * 4 + 2] + red[tid * 4 + 3];
}

// ---------------------------------------------------------------------------
// scatter committed level results into live h / hdot (wave per row)
__global__ __launch_bounds__(256)
void commit_kernel(const int* __restrict__ pcnt, const int* __restrict__ rows,
                   const float* __restrict__ h_stage, const float* __restrict__ hdot_stage,
                   float* __restrict__ h, float* __restrict__ hdot)
{
    int cnt = *pcnt;
    int wv = threadIdx.x >> 6, lane = threadIdx.x & 63;
    int r0 = blockIdx.x * 4 + wv;
    int nw = gridDim.x * 4;
    int d = lane << 1;
    for (int r = r0; r < cnt; r += nw) {
        int n = rows[r];
        float2 v = *reinterpret_cast<const float2*>(h_stage + (size_t)r * 128 + d);
        *reinterpret_cast<float2*>(h + (size_t)n * 128 + d) = v;
        if (lane == 0) hdot[n] = hdot_stage[r];
    }
}

// ---------------------------------------------------------------------------
__global__ __launch_bounds__(256)
void relu_kernel(const float* __restrict__ h, float* __restrict__ out)
{
    int idx = (blockIdx.x * 256 + threadIdx.x) * 4;
    float4 v = *reinterpret_cast<const float4*>(h + idx);
    v.x = fmaxf(v.x, 0.f); v.y = fmaxf(v.y, 0.f);
    v.z = fmaxf(v.z, 0.f); v.w = fmaxf(v.w, 0.f);
    *reinterpret_cast<float4*>(out + idx) = v;
}

// ---------------------------------------------------------------------------
extern "C" void kernel_launch(void* const* d_in, const int* in_sizes, int n_in,
                              void* d_out, int out_size, void* d_ws, size_t ws_size,
                              hipStream_t stream)
{
    (void)in_sizes; (void)n_in; (void)out_size; (void)ws_size;

    const float* x    = (const float*)d_in[0];
    const int*   ei   = (const int*)d_in[1];
    const float* ea   = (const float*)d_in[2];
    const float* We_f = (const float*)d_in[4];
    const float* be_f = (const float*)d_in[5];
    const float* Wa_f = (const float*)d_in[6];
    const float* ba_f = (const float*)d_in[7];
    const float* Wi_f = (const float*)d_in[8];
    const float* Wh_f = (const float*)d_in[9];
    const float* bi_f = (const float*)d_in[10];
    const float* bh_f = (const float*)d_in[11];
    const float* We_b = (const float*)d_in[12];
    const float* be_b = (const float*)d_in[13];
    const float* Wa_b = (const float*)d_in[14];
    const float* ba_b = (const float*)d_in[15];
    const float* Wi_b = (const float*)d_in[16];
    const float* Wh_b = (const float*)d_in[17];
    const float* bi_b = (const float*)d_in[18];
    const float* bh_b = (const float*)d_in[19];
    float* out = (float*)d_out;

    char* p = (char*)d_ws;
    auto carve = [&](size_t bytes) -> char* {
        char* r = p;
        p += (bytes + 255) & ~(size_t)255;
        return r;
    };
    // ---- zeroed region (contiguous, one memset per launch) ----
    int*   counts  = (int*)carve((size_t)16 * 65536 * 4);
    int*   cursor  = (int*)carve((size_t)16 * 65536 * 4);
    int*   flag_f  = (int*)carve((size_t)N_NODES * 4);
    int*   flag_b  = (int*)carve((size_t)N_NODES * 4);
    float* h_fwd   = (float*)carve((size_t)N_NODES * D * 4);   // must start 0
    float* h_cur   = (float*)carve((size_t)N_NODES * D * 4);   // must start 0
    size_t zbytes  = (size_t)((char*)h_cur - (char*)counts) + (size_t)N_NODES * D * 4;
    // ---- rest (fully written each launch before use) ----
    unsigned char* hf_hi = (unsigned char*)carve((size_t)N_NODES * 256); // h_fwd image
    unsigned char* hf_lo = (unsigned char*)carve((size_t)N_NODES * 256);
    int*   cnts    = (int*)carve(256);
    u16*   Whi4    = (u16*)carve((size_t)4 * 49152 * 2);   // WiF,WhF,WiB,WhB hi
    u16*   Wlo4    = (u16*)carve((size_t)4 * 16384 * 2);   // n-gate rows lo
    unsigned char* x_hi  = (unsigned char*)carve((size_t)N_NODES * 256);
    unsigned char* x_lo  = (unsigned char*)carve((size_t)N_NODES * 256);
    float* h_stage = (float*)carve((size_t)N_NODES * D * 4);
    float* hdot_stage = (float*)carve((size_t)N_NODES * 4);
    float* u_f     = (float*)carve((size_t)D * 4);
    float* u_b     = (float*)carve((size_t)D * 4);
    float* cst     = (float*)carve(16);
    float* edot_f  = (float*)carve((size_t)E_EDGES * 4);
    float* edot_b  = (float*)carve((size_t)E_EDGES * 4);
    int*   offs    = (int*)carve((size_t)16 * OSTR * 4);
    int2*  csr     = (int2*)carve((size_t)16 * EL * 8);
    int*   rows    = (int*)carve((size_t)16 * 65536 * 4);
    float* qdot    = (float*)carve((size_t)N_NODES * 4);
    float* hdot    = (float*)carve((size_t)N_NODES * 4);

    hipMemsetAsync(counts, 0, zbytes, stream);
    prep_kernel<<<1, 256, 0, stream>>>(We_f, Wa_f, be_f, ba_f, We_b, Wa_b, be_b, ba_b,
                                       u_f, u_b, cst);
    convert_w<<<dim3(192, 4), 256, 0, stream>>>(Wi_f, Wh_f, Wi_b, Wh_b, Whi4, Wlo4);
    convert_x<<<16384, 256, 0, stream>>>(x, x_hi, x_lo);
    count_flags<<<E_EDGES / 256, 256, 0, stream>>>(ei, counts, flag_f, flag_b);
    edot_kernel<<<E_EDGES / 4, 256, 0, stream>>>(ea, u_f, u_b, cst, edot_f, edot_b);
    scan_compact<<<16, 1024, 0, stream>>>(counts, offs, rows, cnts);
    fill_csr<<<2 * E_EDGES / 256, 256, 0, stream>>>(ei, edot_f, edot_b, offs, cursor, csr);

    for (int dir = 0; dir < 2; ++dir) {
        const float* hp   = dir == 0 ? x : h_fwd;
        float*       h    = dir == 0 ? h_fwd : h_cur;
        const unsigned char* hp_hi = dir == 0 ? x_hi : hf_hi;
        const unsigned char* hp_lo = dir == 0 ? x_lo : hf_lo;
        unsigned char* h_hi = hf_hi;           // only written when dir==0
        unsigned char* h_lo = hf_lo;
        int write_img = (dir == 0);
        const u16* Wihi = Whi4 + (size_t)(dir * 2) * 49152;
        const u16* Whhi = Whi4 + (size_t)(dir * 2 + 1) * 49152;
        const u16* Wilo = Wlo4 + (size_t)(dir * 2) * 16384;
        const u16* Whlo = Wlo4 + (size_t)(dir * 2 + 1) * 16384;
        const float* Wi   = dir == 0 ? Wi_f : Wi_b;
        const float* bi   = dir == 0 ? bi_f : bi_b;
        const float* bh   = dir == 0 ? bh_f : bh_b;
        const float* wa   = dir == 0 ? Wa_f : Wa_b;
        const int*   flag = dir == 0 ? flag_f : flag_b;

        root_init<<<N_NODES / 4, 256, 0, stream>>>(hp, flag, Wi, bi, bh, wa,
                                                   h, h_hi, h_lo, write_img, qdot, hdot);

        for (int t = 0; t < LVLS; ++t) {
            int lv = dir == 0 ? t : (LVLS - 1 - t);
            int dl = dir * LVLS + lv;
            level_kernel<<<512, 512, 0, stream>>>(
                cnts + dl, rows + (size_t)dl * 65536, offs + (size_t)dl * OSTR,
                csr + (size_t)dl * EL, qdot, hdot, h,
                hp_hi, hp_lo, Whhi, Whlo, Wihi, Wilo,
                bi, bh, wa, h_stage, hdot_stage, h_hi, h_lo, write_img);
            commit_kernel<<<1024, 256, 0, stream>>>(
                cnts + dl, rows + (size_t)dl * 65536, h_stage, hdot_stage, h, hdot);
        }
    }
    relu_kernel<<<(N_NODES * D) / 1024, 256, 0, stream>>>(h_cur, out);
}

// Round 14
// 1479.833 us; speedup vs baseline: 1.4559x; 1.4559x over previous
//
#include <hip/hip_runtime.h>
#include <cstdint>
#include <cstddef>

constexpr int N_NODES = 65536;
constexpr int D       = 128;
constexpr int E_EDGES = 524288;
constexpr int LVLS    = 8;
constexpr int EL      = E_EDGES / LVLS;   // 65536
constexpr int OSTR    = 65540;            // offs segment stride (16B-aligned)

typedef unsigned int  u32;
typedef unsigned short u16;
typedef __attribute__((ext_vector_type(8)))  short short8;   // 8 bf16 (4 VGPR)
typedef __attribute__((ext_vector_type(16))) float f32x16;

__device__ __forceinline__ float sigmoidf_(float x) { return 1.0f / (1.0f + expf(-x)); }

__device__ __forceinline__ u32 bf_hi(float f) {           // f32 -> bf16 bits (RNE)
    u32 x = __float_as_uint(f);
    return (x + 0x7fffu + ((x >> 16) & 1u)) >> 16;
}
__device__ __forceinline__ float bf_f(u32 hbits) { return __uint_as_float(hbits << 16); }

// Swizzled byte offset inside a [rows][32 bf16] LDS tile (64B rows).
__device__ __forceinline__ int swz(int row, int kbyte) {
    return row * 64 + (kbyte ^ ((row & 3) << 4));
}

// wave-level async global->LDS DMA: 64 lanes x 16B, dest wave-uniform.
__device__ __forceinline__ void gload_lds16(const void* g, void* l) {
    __builtin_amdgcn_global_load_lds(
        (const __attribute__((address_space(1))) unsigned int*)g,
        (__attribute__((address_space(3))) unsigned int*)l, 16, 0, 0);
}

__device__ __forceinline__ float wave_sum(float v) {
#pragma unroll
    for (int off = 32; off > 0; off >>= 1) v += __shfl_down(v, off, 64);
    return v;
}

// ---------------------------------------------------------------------------
__global__ __launch_bounds__(256)
void prep_kernel(const float* __restrict__ We_f, const float* __restrict__ Wa_f,
                 const float* __restrict__ be_f, const float* __restrict__ ba_f,
                 const float* __restrict__ We_b, const float* __restrict__ Wa_b,
                 const float* __restrict__ be_b, const float* __restrict__ ba_b,
                 float* __restrict__ u_f, float* __restrict__ u_b, float* __restrict__ cst)
{
    int t = threadIdx.x;
    if (t < 128) {
        float s = 0.f;
        for (int d = 0; d < 128; ++d) s = fmaf(We_f[d * 128 + t], Wa_f[128 + d], s);
        u_f[t] = s;
    } else {
        int c = t - 128;
        float s = 0.f;
        for (int d = 0; d < 128; ++d) s = fmaf(We_b[d * 128 + c], Wa_b[128 + d], s);
        u_b[c] = s;
    }
    if (t == 0) {
        float s = 0.f;
        for (int d = 0; d < 128; ++d) s = fmaf(be_f[d], Wa_f[128 + d], s);
        cst[0] = s + ba_f[0];
    }
    if (t == 255) {
        float s = 0.f;
        for (int d = 0; d < 128; ++d) s = fmaf(be_b[d], Wa_b[128 + d], s);
        cst[1] = s + ba_b[0];
    }
}

// ---------------------------------------------------------------------------
// weights -> LINEAR bf16 split: hi[m][384][128], lo[m][128][128] (rows 256..383)
__global__ __launch_bounds__(256)
void convert_w(const float* __restrict__ W0, const float* __restrict__ W1,
               const float* __restrict__ W2, const float* __restrict__ W3,
               u16* __restrict__ hi4, u16* __restrict__ lo4)
{
    const float* Ws[4] = {W0, W1, W2, W3};
    int m = blockIdx.y;
    int i = blockIdx.x * 256 + threadIdx.x;        // < 49152 ; i = rw*128 + k
    int rw = i >> 7, k = i & 127;
    float v = Ws[m][i];
    u32 hb = bf_hi(v);
    hi4[(size_t)m * 49152 + i] = (u16)hb;
    if (rw >= 256)
        lo4[(size_t)m * 16384 + (size_t)(rw - 256) * 128 + k] = (u16)bf_hi(v - bf_f(hb));
}

// ---------------------------------------------------------------------------
// x -> linear bf16 split images (256B/row each)
__global__ __launch_bounds__(256)
void convert_x(const float* __restrict__ x, unsigned char* __restrict__ xhi,
               unsigned char* __restrict__ xlo)
{
    int idx = blockIdx.x * 256 + threadIdx.x;      // < 65536*64
    int n = idx >> 6, d = (idx & 63) << 1;
    float2 v = *reinterpret_cast<const float2*>(x + (size_t)n * 128 + d);
    u32 h0 = bf_hi(v.x), h1 = bf_hi(v.y);
    u32 l0 = bf_hi(v.x - bf_f(h0)), l1 = bf_hi(v.y - bf_f(h1));
    size_t off = (size_t)n * 256 + (size_t)d * 2;
    *reinterpret_cast<u32*>(xhi + off) = h0 | (h1 << 16);
    *reinterpret_cast<u32*>(xlo + off) = l0 | (l1 << 16);
}

// ---------------------------------------------------------------------------
// edot (wave per edge) + per-(dir,level) counts + flags (lane 0)
__global__ __launch_bounds__(256)
void edot_count(const float* __restrict__ ea, const float* __restrict__ u_f,
                const float* __restrict__ u_b, const float* __restrict__ cst,
                const int* __restrict__ ei,
                float* __restrict__ edot_f, float* __restrict__ edot_b,
                int* __restrict__ counts, int* __restrict__ flag_f,
                int* __restrict__ flag_b)
{
    int wv = threadIdx.x >> 6, lane = threadIdx.x & 63;
    int e = blockIdx.x * 4 + wv;
    if (e >= E_EDGES) return;
    int d = lane << 1;
    float2 v  = *reinterpret_cast<const float2*>(ea + (size_t)e * 128 + d);
    float2 uf = *reinterpret_cast<const float2*>(u_f + d);
    float2 ub = *reinterpret_cast<const float2*>(u_b + d);
    float af = wave_sum(v.x * uf.x + v.y * uf.y);
    float ab = wave_sum(v.x * ub.x + v.y * ub.y);
    if (lane == 0) {
        edot_f[e] = af + cst[0];
        edot_b[e] = ab + cst[1];
        int lv = e >> 16;
        int s = ei[e], t = ei[E_EDGES + e];
        atomicAdd(&counts[(size_t)lv * 65536 + t], 1);           // fwd: target=dst
        atomicAdd(&counts[(size_t)(8 + lv) * 65536 + s], 1);     // bwd: target=src
        flag_f[t] = 1;
        flag_b[s] = 1;
    }
}

// ---------------------------------------------------------------------------
__global__ __launch_bounds__(1024)
void scan_compact(const int* __restrict__ counts, int* __restrict__ offs,
                  int* __restrict__ rows, int* __restrict__ cnts)
{
    __shared__ int sbuf[1024];
    __shared__ int nbuf[1024];
    int dl = blockIdx.x;
    const int4* c4 = reinterpret_cast<const int4*>(counts + (size_t)dl * 65536);
    int* o = offs + (size_t)dl * OSTR;
    int* rw = rows + (size_t)dl * 65536;
    int t = threadIdx.x;
    int cv[64];
#pragma unroll 4
    for (int k4 = 0; k4 < 16; ++k4) {
        int4 v = c4[t * 16 + k4];
        cv[k4 * 4 + 0] = v.x; cv[k4 * 4 + 1] = v.y;
        cv[k4 * 4 + 2] = v.z; cv[k4 * 4 + 3] = v.w;
    }
    int s = 0, nz = 0;
#pragma unroll
    for (int k = 0; k < 64; ++k) { s += cv[k]; nz += (cv[k] > 0); }
    sbuf[t] = s;
    nbuf[t] = nz;
    __syncthreads();
    int val = s, nval = nz;
    for (int off = 1; off < 1024; off <<= 1) {
        int add  = (t >= off) ? sbuf[t - off] : 0;
        int nadd = (t >= off) ? nbuf[t - off] : 0;
        __syncthreads();
        val += add;
        nval += nadd;
        sbuf[t] = val;
        nbuf[t] = nval;
        __syncthreads();
    }
    int run  = val - s;
    int nrun = nval - nz;
    int base = t * 64;
    int4* o4 = reinterpret_cast<int4*>(o + base);
#pragma unroll 4
    for (int k4 = 0; k4 < 16; ++k4) {
        int4 ov;
        ov.x = run; run += cv[k4 * 4 + 0];
        ov.y = run; run += cv[k4 * 4 + 1];
        ov.z = run; run += cv[k4 * 4 + 2];
        ov.w = run; run += cv[k4 * 4 + 3];
        o4[k4] = ov;
#pragma unroll
        for (int q = 0; q < 4; ++q)
            if (cv[k4 * 4 + q] > 0) rw[nrun++] = base + k4 * 4 + q;
    }
    if (t == 1023) { o[65536] = val; cnts[dl] = nval; }
}

// ---------------------------------------------------------------------------
__global__ __launch_bounds__(256)
void fill_csr(const int* __restrict__ ei, const float* __restrict__ edot_f,
              const float* __restrict__ edot_b, const int* __restrict__ offs,
              int* __restrict__ cursor, int2* __restrict__ csr)
{
    int idx = blockIdx.x * 256 + threadIdx.x;       // < 2E
    int dir = idx >= E_EDGES;
    int ge = dir ? idx - E_EDGES : idx;
    int lv = ge >> 16;
    int dl = dir * 8 + lv;
    int i = dir ? ei[ge] : ei[E_EDGES + ge];
    int j = dir ? ei[E_EDGES + ge] : ei[ge];
    int pos = offs[(size_t)dl * OSTR + i] + atomicAdd(&cursor[(size_t)dl * 65536 + i], 1);
    int2 v;
    v.x = j;
    v.y = __float_as_int(dir ? edot_b[ge] : edot_f[ge]);
    csr[(size_t)dl * EL + pos] = v;
}

// ---------------------------------------------------------------------------
// qdot for all nodes; exact-f32 GRU for roots (writes h f32 + split images).
__global__ __launch_bounds__(256)
void root_init(const float* __restrict__ hp, const int* __restrict__ flag,
               const float* __restrict__ Wi, const float* __restrict__ bi,
               const float* __restrict__ bh, const float* __restrict__ wa,
               float* __restrict__ h, unsigned char* __restrict__ h_hi,
               unsigned char* __restrict__ h_lo, int write_img,
               float* __restrict__ qdot, float* __restrict__ hdot)
{
    int wv = threadIdx.x >> 6, lane = threadIdx.x & 63;
    int n = blockIdx.x * 4 + wv;
    int d = lane << 1;
    const float* hprow = hp + (size_t)n * 128;
    float2 hpv = *reinterpret_cast<const float2*>(hprow + d);
    float qd = wave_sum(hpv.x * wa[d] + hpv.y * wa[d + 1]);
    if (lane == 0) qdot[n] = qd;
    bool root = (flag[n] == 0);
    float hv[2] = {0.f, 0.f};
    if (root) {   // rare; exact f32 path
#pragma unroll
        for (int q = 0; q < 2; ++q) {
            int dd = d + q;
            float g0 = bi[dd], g1 = bi[dd + 128], g2 = bi[dd + 256];
            for (int k = 0; k < 128; ++k) {
                float a = hprow[k];
                g0 = fmaf(a, Wi[(size_t)dd * 128 + k], g0);
                g1 = fmaf(a, Wi[(size_t)(dd + 128) * 128 + k], g1);
                g2 = fmaf(a, Wi[(size_t)(dd + 256) * 128 + k], g2);
            }
            float rr = sigmoidf_(g0 + bh[dd]);
            float zz = sigmoidf_(g1 + bh[dd + 128]);
            float nn = tanhf(g2 + rr * bh[dd + 256]);
            hv[q] = (1.f - zz) * nn;            // hidden = 0 for roots
        }
        *reinterpret_cast<float2*>(h + (size_t)n * 128 + d) = make_float2(hv[0], hv[1]);
        if (write_img) {
            u32 hb0 = bf_hi(hv[0]), hb1 = bf_hi(hv[1]);
            u32 lb0 = bf_hi(hv[0] - bf_f(hb0)), lb1 = bf_hi(hv[1] - bf_f(hb1));
            size_t off = (size_t)n * 256 + (size_t)d * 2;
            *reinterpret_cast<u32*>(h_hi + off) = hb0 | (hb1 << 16);
            *reinterpret_cast<u32*>(h_lo + off) = lb0 | (lb1 << 16);
        }
    }
    float hd = wave_sum(hv[0] * wa[128 + d] + hv[1] * wa[128 + d + 1]);
    if (lane == 0) hdot[n] = root ? hd : 0.f;
}

// ---------------------------------------------------------------------------
// Half-wave per target: softmax aggregation; writes msg as bf16-hi image only.
__global__ __launch_bounds__(256)
void attn_msg(const int* __restrict__ pcnt, const int* __restrict__ rows,
              const int* __restrict__ offs, const int2* __restrict__ csr,
              const float* __restrict__ qdot, const float* __restrict__ hdot,
              const float* __restrict__ h, unsigned char* __restrict__ msg_hi)
{
    int cnt = *pcnt;
    int l31 = threadIdx.x & 31;
    int hid = (blockIdx.x * 256 + threadIdx.x) >> 5;
    int nh = (gridDim.x * 256) >> 5;
    int d4 = l31 << 2;
    for (int r = hid; r < cnt; r += nh) {
        int i = rows[r];
        int o0 = offs[i], o1 = offs[i + 1];
        float qi = qdot[i];
        float den = 0.f;
        float4 acc = make_float4(0.f, 0.f, 0.f, 0.f);
        int2 je = csr[o0];
        for (int e = o0; e < o1; ++e) {
            int en = e + 1;
            int2 jn = (en < o1) ? csr[en] : je;   // one-ahead prefetch
            float ex = expf(qi + hdot[je.x] + __int_as_float(je.y));
            float4 hv = *reinterpret_cast<const float4*>(h + (size_t)je.x * 128 + d4);
            den += ex;
            acc.x = fmaf(ex, hv.x, acc.x);
            acc.y = fmaf(ex, hv.y, acc.y);
            acc.z = fmaf(ex, hv.z, acc.z);
            acc.w = fmaf(ex, hv.w, acc.w);
            je = jn;
        }
        float inv = 1.f / den;
        u32 h0 = bf_hi(acc.x * inv), h1 = bf_hi(acc.y * inv);
        u32 h2 = bf_hi(acc.z * inv), h3 = bf_hi(acc.w * inv);
        *reinterpret_cast<uint2*>(msg_hi + (size_t)r * 256 + (size_t)d4 * 2) =
            make_uint2(h0 | (h1 << 16), h2 | (h3 << 16));
    }
}

// ---------------------------------------------------------------------------
// Dual-phase GEMM + GRU. 64-row tile, 256 thr (4 waves), LDS exactly 80KB ->
// 2 blocks/CU (cross-block overlap hides barrier/DMA stalls).
// Phase A (t=0..3): acc  = msg_hi[dense] @ Wh_hi^T    (r/z/n single-term)
// Phase B (t=4..7): acc += hp[gather](hi+lo) @ Wi^T   (r/z 2-term, n 3-term)
// red[] aliased onto Bs after the loop; rows[] read from global (no rowsLds).
__global__ __launch_bounds__(256, 2)
void gemm_gru(const unsigned char* __restrict__ msg_hi,
              const unsigned char* __restrict__ hp_hi, const unsigned char* __restrict__ hp_lo,
              const u16* __restrict__ Whhi,
              const u16* __restrict__ Wihi, const u16* __restrict__ Wilo,
              const int* __restrict__ pcnt, const int* __restrict__ rows,
              const float* __restrict__ bi, const float* __restrict__ bh,
              const float* __restrict__ wa,
              float* __restrict__ h, unsigned char* __restrict__ h_hi,
              unsigned char* __restrict__ h_lo, int write_img,
              float* __restrict__ hdot)
{
    __shared__ __align__(16) unsigned char smem[16384 + 65536];  // As 2x8K | Bs 2x32K
    unsigned char* As = smem;
    unsigned char* Bs = smem + 16384;

    const int tid = threadIdx.x;
    const int cnt = *pcnt;
    const int row0 = blockIdx.x * 64;
    if (row0 >= cnt) return;

    const int lane = tid & 63, wv = tid >> 6;
    const int q = wv;                 // col slice
    const int l31 = lane & 31, l5 = lane >> 5;

    // A-source per-lane offsets (swizzle folded into source address)
    const int rwA = wv * 16 + (lane >> 2);                 // 0..63
    const int slA = ((lane & 3) << 4) ^ ((rwA & 3) << 4);
    int garA = row0 + rwA;
    const size_t baseA0 = (size_t)garA * 256 + slA;        // dense msg rows
    int rowA1 = rows[garA < cnt ? garA : 0];
    const size_t baseA1 = (size_t)rowA1 * 256 + slA;       // gathered hp rows
    // B-source offsets: hi 6 DMAs (384 rows), lo 2 DMAs (128 rows)
    size_t bsrc[6];
#pragma unroll
    for (int k = 0; k < 6; ++k) {
        int rwB = wv * 96 + k * 16 + (lane >> 2);
        bsrc[k] = (size_t)rwB * 256 + (((lane & 3) << 4) ^ ((rwB & 3) << 4));
    }
    size_t lsrc[2];
#pragma unroll
    for (int k = 0; k < 2; ++k) {
        int rwL = wv * 32 + k * 16 + (lane >> 2);
        lsrc[k] = (size_t)rwL * 256 + (((lane & 3) << 4) ^ ((rwL & 3) << 4));
    }

    f32x16 acc[2][3];
#pragma unroll
    for (int mt = 0; mt < 2; ++mt)
#pragma unroll
        for (int g = 0; g < 3; ++g) acc[mt][g] = (f32x16)0.0f;
    f32x16 ghn[2];

    auto STAGE = [&](int tt) {
        int b = tt & 1;
        size_t ko = (size_t)(tt & 3) * 64;
        unsigned char* Bd = Bs + b * 32768;
        if (tt < 4) {      // phase A: msg hi + Wh hi (7 DMA/wave)
            gload_lds16(msg_hi + baseA0 + ko, As + b * 8192 + wv * 1024);
#pragma unroll
            for (int k = 0; k < 6; ++k)
                gload_lds16((const unsigned char*)Whhi + bsrc[k] + ko, Bd + (wv * 6 + k) * 1024);
        } else {           // phase B: hp hi+lo + Wi hi+lo (10 DMA/wave)
            gload_lds16(hp_hi + baseA1 + ko, As + b * 8192 + wv * 1024);
            gload_lds16(hp_lo + baseA1 + ko, As + b * 8192 + 4096 + wv * 1024);
#pragma unroll
            for (int k = 0; k < 6; ++k)
                gload_lds16((const unsigned char*)Wihi + bsrc[k] + ko, Bd + (wv * 6 + k) * 1024);
#pragma unroll
            for (int k = 0; k < 2; ++k)
                gload_lds16((const unsigned char*)Wilo + lsrc[k] + ko, Bd + 24576 + (wv * 2 + k) * 1024);
        }
    };

    STAGE(0);
    for (int t = 0; t < 8; ++t) {
        if (t < 7) STAGE(t + 1);
        __builtin_amdgcn_sched_barrier(0);
        if (t < 3)      asm volatile("s_waitcnt vmcnt(7)");    // next = phase-A tile
        else if (t < 7) asm volatile("s_waitcnt vmcnt(10)");   // next = phase-B tile
        else            asm volatile("s_waitcnt vmcnt(0)");
        __builtin_amdgcn_s_barrier();
        __builtin_amdgcn_sched_barrier(0);

        const unsigned char* Ab = As + (t & 1) * 8192;
        const unsigned char* Bb = Bs + (t & 1) * 32768;
#pragma unroll
        for (int kh = 0; kh < 2; ++kh) {
            short8 b0 = *reinterpret_cast<const short8*>(
                Bb + swz(q * 32 + l31, kh * 32 + l5 * 16));
            short8 b1 = *reinterpret_cast<const short8*>(
                Bb + swz(q * 32 + 128 + l31, kh * 32 + l5 * 16));
            short8 b2 = *reinterpret_cast<const short8*>(
                Bb + swz(q * 32 + 256 + l31, kh * 32 + l5 * 16));
            short8 ah[2];
#pragma unroll
            for (int mt = 0; mt < 2; ++mt)
                ah[mt] = *reinterpret_cast<const short8*>(
                    Ab + swz(mt * 32 + l31, kh * 32 + l5 * 16));
            if (t < 4) {   // phase A: single-term
#pragma unroll
                for (int mt = 0; mt < 2; ++mt) {
                    acc[mt][0] = __builtin_amdgcn_mfma_f32_32x32x16_bf16(ah[mt], b0, acc[mt][0], 0, 0, 0);
                    acc[mt][1] = __builtin_amdgcn_mfma_f32_32x32x16_bf16(ah[mt], b1, acc[mt][1], 0, 0, 0);
                    acc[mt][2] = __builtin_amdgcn_mfma_f32_32x32x16_bf16(ah[mt], b2, acc[mt][2], 0, 0, 0);
                }
            } else {       // phase B: r/z 2-term, n 3-term
                short8 bl2 = *reinterpret_cast<const short8*>(
                    Bb + 24576 + swz(q * 32 + l31, kh * 32 + l5 * 16));
                short8 al[2];
#pragma unroll
                for (int mt = 0; mt < 2; ++mt)
                    al[mt] = *reinterpret_cast<const short8*>(
                        Ab + 4096 + swz(mt * 32 + l31, kh * 32 + l5 * 16));
#pragma unroll
                for (int mt = 0; mt < 2; ++mt) {
                    acc[mt][0] = __builtin_amdgcn_mfma_f32_32x32x16_bf16(ah[mt], b0, acc[mt][0], 0, 0, 0);
                    acc[mt][0] = __builtin_amdgcn_mfma_f32_32x32x16_bf16(al[mt], b0, acc[mt][0], 0, 0, 0);
                    acc[mt][1] = __builtin_amdgcn_mfma_f32_32x32x16_bf16(ah[mt], b1, acc[mt][1], 0, 0, 0);
                    acc[mt][1] = __builtin_amdgcn_mfma_f32_32x32x16_bf16(al[mt], b1, acc[mt][1], 0, 0, 0);
                    acc[mt][2] = __builtin_amdgcn_mfma_f32_32x32x16_bf16(ah[mt], b2, acc[mt][2], 0, 0, 0);
                    acc[mt][2] = __builtin_amdgcn_mfma_f32_32x32x16_bf16(ah[mt], bl2, acc[mt][2], 0, 0, 0);
                    acc[mt][2] = __builtin_amdgcn_mfma_f32_32x32x16_bf16(al[mt], b2, acc[mt][2], 0, 0, 0);
                }
            }
        }
        if (t == 3) {                        // end of phase A: stash gh_n
            ghn[0] = acc[0][2];
            ghn[1] = acc[1][2];
            acc[0][2] = (f32x16)0.0f;
            acc[1][2] = (f32x16)0.0f;
        }
        __builtin_amdgcn_s_barrier();        // reads done before buf reuse
        __builtin_amdgcn_sched_barrier(0);
    }

    // ---- epilogue (red aliases Bs — dead after the loop)
    __syncthreads();
    float* red = (float*)Bs;                  // [64][4]
    const int d = q * 32 + l31;
    const float wa2d = wa[128 + d];
    const float bi0 = bi[d], bi1 = bi[d + 128], bi2 = bi[d + 256];
    const float bh0 = bh[d], bh1 = bh[d + 128], bh2 = bh[d + 256];

#pragma unroll
    for (int mt = 0; mt < 2; ++mt)
#pragma unroll
        for (int rg = 0; rg < 16; ++rg) {
            int rl = mt * 32 + (rg & 3) + ((rg >> 2) << 3) + (l5 << 2);
            int gr = row0 + rl;
            bool ok = gr < cnt;
            int n = rows[ok ? gr : 0];
            float mval = bf_f(*reinterpret_cast<const u16*>(
                msg_hi + (size_t)gr * 256 + (size_t)d * 2));
            float rr = sigmoidf_(acc[mt][0][rg] + bi0 + bh0);
            float zz = sigmoidf_(acc[mt][1][rg] + bi1 + bh1);
            float nn = tanhf(acc[mt][2][rg] + bi2 + rr * (ghn[mt][rg] + bh2));
            float hv = (1.f - zz) * nn + zz * mval;    // hidden = msg
            if (ok) {
                h[(size_t)n * 128 + d] = hv;
                if (write_img) {
                    u32 hb = bf_hi(hv);
                    *reinterpret_cast<u16*>(h_hi + (size_t)n * 256 + (size_t)d * 2) = (u16)hb;
                    *reinterpret_cast<u16*>(h_lo + (size_t)n * 256 + (size_t)d * 2) =
                        (u16)bf_hi(hv - bf_f(hb));
                }
            }
            float pd = hv * wa2d;
#pragma unroll
            for (int o = 1; o < 32; o <<= 1) pd += __shfl_xor(pd, o, 64);
            if (l31 == 0) red[rl * 4 + q] = pd;
        }
    __syncthreads();
    if (tid < 64 && row0 + tid < cnt) {
        int n = rows[row0 + tid];
        hdot[n] = red[tid * 4] + red[tid * 4 + 1] + red[tid * 4 + 2] + red[tid * 4 + 3];
    }
}

// ---------------------------------------------------------------------------
__global__ __launch_bounds__(256)
void relu_kernel(const float* __restrict__ h, float* __restrict__ out)
{
    int idx = (blockIdx.x * 256 + threadIdx.x) * 4;
    float4 v = *reinterpret_cast<const float4*>(h + idx);
    v.x = fmaxf(v.x, 0.f); v.y = fmaxf(v.y, 0.f);
    v.z = fmaxf(v.z, 0.f); v.w = fmaxf(v.w, 0.f);
    *reinterpret_cast<float4*>(out + idx) = v;
}

// ---------------------------------------------------------------------------
extern "C" void kernel_launch(void* const* d_in, const int* in_sizes, int n_in,
                              void* d_out, int out_size, void* d_ws, size_t ws_size,
                              hipStream_t stream)
{
    (void)in_sizes; (void)n_in; (void)out_size; (void)ws_size;

    const float* x    = (const float*)d_in[0];
    const int*   ei   = (const int*)d_in[1];
    const float* ea   = (const float*)d_in[2];
    const float* We_f = (const float*)d_in[4];
    const float* be_f = (const float*)d_in[5];
    const float* Wa_f = (const float*)d_in[6];
    const float* ba_f = (const float*)d_in[7];
    const float* Wi_f = (const float*)d_in[8];
    const float* Wh_f = (const float*)d_in[9];
    const float* bi_f = (const float*)d_in[10];
    const float* bh_f = (const float*)d_in[11];
    const float* We_b = (const float*)d_in[12];
    const float* be_b = (const float*)d_in[13];
    const float* Wa_b = (const float*)d_in[14];
    const float* ba_b = (const float*)d_in[15];
    const float* Wi_b = (const float*)d_in[16];
    const float* Wh_b = (const float*)d_in[17];
    const float* bi_b = (const float*)d_in[18];
    const float* bh_b = (const float*)d_in[19];
    float* out = (float*)d_out;

    char* p = (char*)d_ws;
    auto carve = [&](size_t bytes) -> char* {
        char* r = p;
        p += (bytes + 255) & ~(size_t)255;
        return r;
    };
    // ---- zeroed region (contiguous, one memset per launch) ----
    int*   counts  = (int*)carve((size_t)16 * 65536 * 4);
    int*   cursor  = (int*)carve((size_t)16 * 65536 * 4);
    int*   flag_f  = (int*)carve((size_t)N_NODES * 4);
    int*   flag_b  = (int*)carve((size_t)N_NODES * 4);
    float* h_fwd   = (float*)carve((size_t)N_NODES * D * 4);   // must start 0
    float* h_cur   = (float*)carve((size_t)N_NODES * D * 4);   // must start 0
    size_t zbytes  = (size_t)((char*)h_cur - (char*)counts) + (size_t)N_NODES * D * 4;
    // ---- rest (fully written each launch before use) ----
    unsigned char* hf_hi = (unsigned char*)carve((size_t)N_NODES * 256); // h_fwd image
    unsigned char* hf_lo = (unsigned char*)carve((size_t)N_NODES * 256);
    int*   cnts    = (int*)carve(256);
    u16*   Whi4    = (u16*)carve((size_t)4 * 49152 * 2);   // WiF,WhF,WiB,WhB hi
    u16*   Wlo4    = (u16*)carve((size_t)4 * 16384 * 2);   // n-gate rows lo
    unsigned char* x_hi  = (unsigned char*)carve((size_t)N_NODES * 256);
    unsigned char* x_lo  = (unsigned char*)carve((size_t)N_NODES * 256);
    unsigned char* msg_hi= (unsigned char*)carve((size_t)N_NODES * 256);
    float* u_f     = (float*)carve((size_t)D * 4);
    float* u_b     = (float*)carve((size_t)D * 4);
    float* cst     = (float*)carve(16);
    float* edot_f  = (float*)carve((size_t)E_EDGES * 4);
    float* edot_b  = (float*)carve((size_t)E_EDGES * 4);
    int*   offs    = (int*)carve((size_t)16 * OSTR * 4);
    int2*  csr     = (int2*)carve((size_t)16 * EL * 8);
    int*   rows    = (int*)carve((size_t)16 * 65536 * 4);
    float* qdot    = (float*)carve((size_t)N_NODES * 4);
    float* hdot    = (float*)carve((size_t)N_NODES * 4);

    hipMemsetAsync(counts, 0, zbytes, stream);
    prep_kernel<<<1, 256, 0, stream>>>(We_f, Wa_f, be_f, ba_f, We_b, Wa_b, be_b, ba_b,
                                       u_f, u_b, cst);
    convert_w<<<dim3(192, 4), 256, 0, stream>>>(Wi_f, Wh_f, Wi_b, Wh_b, Whi4, Wlo4);
    convert_x<<<16384, 256, 0, stream>>>(x, x_hi, x_lo);
    edot_count<<<E_EDGES / 4, 256, 0, stream>>>(ea, u_f, u_b, cst, ei,
                                                edot_f, edot_b, counts, flag_f, flag_b);
    scan_compact<<<16, 1024, 0, stream>>>(counts, offs, rows, cnts);
    fill_csr<<<2 * E_EDGES / 256, 256, 0, stream>>>(ei, edot_f, edot_b, offs, cursor, csr);

    for (int dir = 0; dir < 2; ++dir) {
        const float* hp   = dir == 0 ? x : h_fwd;
        float*       h    = dir == 0 ? h_fwd : h_cur;
        const unsigned char* hp_hi = dir == 0 ? x_hi : hf_hi;
        const unsigned char* hp_lo = dir == 0 ? x_lo : hf_lo;
        unsigned char* h_hi = hf_hi;           // only written when dir==0
        unsigned char* h_lo = hf_lo;
        int write_img = (dir == 0);
        const u16* Wihi = Whi4 + (size_t)(dir * 2) * 49152;
        const u16* Whhi = Whi4 + (size_t)(dir * 2 + 1) * 49152;
        const u16* Wilo = Wlo4 + (size_t)(dir * 2) * 16384;
        const float* Wi   = dir == 0 ? Wi_f : Wi_b;
        const float* bi   = dir == 0 ? bi_f : bi_b;
        const float* bh   = dir == 0 ? bh_f : bh_b;
        const float* wa   = dir == 0 ? Wa_f : Wa_b;
        const int*   flag = dir == 0 ? flag_f : flag_b;

        root_init<<<N_NODES / 4, 256, 0, stream>>>(hp, flag, Wi, bi, bh, wa,
                                                   h, h_hi, h_lo, write_img, qdot, hdot);

        for (int t = 0; t < LVLS; ++t) {
            int lv = dir == 0 ? t : (LVLS - 1 - t);
            int dl = dir * LVLS + lv;
            attn_msg<<<2048, 256, 0, stream>>>(
                cnts + dl, rows + (size_t)dl * 65536, offs + (size_t)dl * OSTR,
                csr + (size_t)dl * EL, qdot, hdot, h, msg_hi);
            gemm_gru<<<1024, 256, 0, stream>>>(
                msg_hi, hp_hi, hp_lo, Whhi, Wihi, Wilo,
                cnts + dl, rows + (size_t)dl * 65536,
                bi, bh, wa, h, h_hi, h_lo, write_img, hdot);
        }
    }
    relu_kernel<<<(N_NODES * D) / 1024, 256, 0, stream>>>(h_cur, out);
}

// Round 15
// 1416.175 us; speedup vs baseline: 1.5213x; 1.0450x over previous
//
#include <hip/hip_runtime.h>
#include <cstdint>
#include <cstddef>

constexpr int N_NODES = 65536;
constexpr int D       = 128;
constexpr int E_EDGES = 524288;
constexpr int LVLS    = 8;
constexpr int EL      = E_EDGES / LVLS;   // 65536
constexpr int OSTR    = 65540;            // offs segment stride (16B-aligned)

typedef unsigned int  u32;
typedef unsigned short u16;
typedef __attribute__((ext_vector_type(8)))  short short8;   // 8 bf16 (4 VGPR)
typedef __attribute__((ext_vector_type(16))) float f32x16;

__device__ __forceinline__ float sigmoidf_(float x) { return 1.0f / (1.0f + expf(-x)); }

__device__ __forceinline__ u32 bf_hi(float f) {           // f32 -> bf16 bits (RNE)
    u32 x = __float_as_uint(f);
    return (x + 0x7fffu + ((x >> 16) & 1u)) >> 16;
}
__device__ __forceinline__ float bf_f(u32 hbits) { return __uint_as_float(hbits << 16); }

// Swizzled byte offset inside a [rows][32 bf16] LDS tile (64B rows).
__device__ __forceinline__ int swz(int row, int kbyte) {
    return row * 64 + (kbyte ^ ((row & 3) << 4));
}

// wave-level async global->LDS DMA: 64 lanes x 16B, dest wave-uniform.
__device__ __forceinline__ void gload_lds16(const void* g, void* l) {
    __builtin_amdgcn_global_load_lds(
        (const __attribute__((address_space(1))) unsigned int*)g,
        (__attribute__((address_space(3))) unsigned int*)l, 16, 0, 0);
}

__device__ __forceinline__ float wave_sum(float v) {
#pragma unroll
    for (int off = 32; off > 0; off >>= 1) v += __shfl_down(v, off, 64);
    return v;
}

// ---------------------------------------------------------------------------
__global__ __launch_bounds__(256)
void prep_kernel(const float* __restrict__ We_f, const float* __restrict__ Wa_f,
                 const float* __restrict__ be_f, const float* __restrict__ ba_f,
                 const float* __restrict__ We_b, const float* __restrict__ Wa_b,
                 const float* __restrict__ be_b, const float* __restrict__ ba_b,
                 float* __restrict__ u_f, float* __restrict__ u_b, float* __restrict__ cst)
{
    int t = threadIdx.x;
    if (t < 128) {
        float s = 0.f;
        for (int d = 0; d < 128; ++d) s = fmaf(We_f[d * 128 + t], Wa_f[128 + d], s);
        u_f[t] = s;
    } else {
        int c = t - 128;
        float s = 0.f;
        for (int d = 0; d < 128; ++d) s = fmaf(We_b[d * 128 + c], Wa_b[128 + d], s);
        u_b[c] = s;
    }
    if (t == 0) {
        float s = 0.f;
        for (int d = 0; d < 128; ++d) s = fmaf(be_f[d], Wa_f[128 + d], s);
        cst[0] = s + ba_f[0];
    }
    if (t == 255) {
        float s = 0.f;
        for (int d = 0; d < 128; ++d) s = fmaf(be_b[d], Wa_b[128 + d], s);
        cst[1] = s + ba_b[0];
    }
}

// ---------------------------------------------------------------------------
// weights -> LINEAR bf16 split: hi[m][384][128], lo[m][128][128] (rows 256..383)
__global__ __launch_bounds__(256)
void convert_w(const float* __restrict__ W0, const float* __restrict__ W1,
               const float* __restrict__ W2, const float* __restrict__ W3,
               u16* __restrict__ hi4, u16* __restrict__ lo4)
{
    const float* Ws[4] = {W0, W1, W2, W3};
    int m = blockIdx.y;
    int i = blockIdx.x * 256 + threadIdx.x;        // < 49152 ; i = rw*128 + k
    int rw = i >> 7, k = i & 127;
    float v = Ws[m][i];
    u32 hb = bf_hi(v);
    hi4[(size_t)m * 49152 + i] = (u16)hb;
    if (rw >= 256)
        lo4[(size_t)m * 16384 + (size_t)(rw - 256) * 128 + k] = (u16)bf_hi(v - bf_f(hb));
}

// ---------------------------------------------------------------------------
// x -> linear bf16 split images (256B/row each)
__global__ __launch_bounds__(256)
void convert_x(const float* __restrict__ x, unsigned char* __restrict__ xhi,
               unsigned char* __restrict__ xlo)
{
    int idx = blockIdx.x * 256 + threadIdx.x;      // < 65536*64
    int n = idx >> 6, d = (idx & 63) << 1;
    float2 v = *reinterpret_cast<const float2*>(x + (size_t)n * 128 + d);
    u32 h0 = bf_hi(v.x), h1 = bf_hi(v.y);
    u32 l0 = bf_hi(v.x - bf_f(h0)), l1 = bf_hi(v.y - bf_f(h1));
    size_t off = (size_t)n * 256 + (size_t)d * 2;
    *reinterpret_cast<u32*>(xhi + off) = h0 | (h1 << 16);
    *reinterpret_cast<u32*>(xlo + off) = l0 | (l1 << 16);
}

// ---------------------------------------------------------------------------
// edot + counts/flags. 8 edges per wave: 8 outstanding loads, 16 independent
// butterfly reductions (ILP hides ds_bpermute latency; R14's wave-per-edge
// serial 6-deep shfl chain was 167us, pure latency).
__global__ __launch_bounds__(256)
void edot_count(const float* __restrict__ ea, const float* __restrict__ u_f,
                const float* __restrict__ u_b, const float* __restrict__ cst,
                const int* __restrict__ ei,
                float* __restrict__ edot_f, float* __restrict__ edot_b,
                int* __restrict__ counts, int* __restrict__ flag_f,
                int* __restrict__ flag_b)
{
    int wv = threadIdx.x >> 6, lane = threadIdx.x & 63;
    int e0 = (blockIdx.x * 4 + wv) * 8;
    int d = lane << 1;
    float2 uf = *reinterpret_cast<const float2*>(u_f + d);
    float2 ub = *reinterpret_cast<const float2*>(u_b + d);
    float af[8], ab[8];
#pragma unroll
    for (int k = 0; k < 8; ++k) {
        float2 v = *reinterpret_cast<const float2*>(ea + (size_t)(e0 + k) * 128 + d);
        af[k] = v.x * uf.x + v.y * uf.y;
        ab[k] = v.x * ub.x + v.y * ub.y;
    }
#pragma unroll
    for (int off = 1; off < 64; off <<= 1) {
#pragma unroll
        for (int k = 0; k < 8; ++k) {
            af[k] += __shfl_xor(af[k], off, 64);
            ab[k] += __shfl_xor(ab[k], off, 64);
        }
    }
    if (lane < 16) {
        int k = lane & 7;
        int e = e0 + k;
        int lv = e >> 16;                 // same for all 8 (e0 % 8 == 0)
        float sf = k == 0 ? af[0] : k == 1 ? af[1] : k == 2 ? af[2] : k == 3 ? af[3] :
                   k == 4 ? af[4] : k == 5 ? af[5] : k == 6 ? af[6] : af[7];
        float sb = k == 0 ? ab[0] : k == 1 ? ab[1] : k == 2 ? ab[2] : k == 3 ? ab[3] :
                   k == 4 ? ab[4] : k == 5 ? ab[5] : k == 6 ? ab[6] : ab[7];
        if (lane < 8) {
            edot_f[e] = sf + cst[0];
            int t = ei[E_EDGES + e];
            atomicAdd(&counts[(size_t)lv * 65536 + t], 1);       // fwd: target=dst
            flag_f[t] = 1;
        } else {
            edot_b[e] = sb + cst[1];
            int s = ei[e];
            atomicAdd(&counts[(size_t)(8 + lv) * 65536 + s], 1); // bwd: target=src
            flag_b[s] = 1;
        }
    }
}

// ---------------------------------------------------------------------------
__global__ __launch_bounds__(1024)
void scan_compact(const int* __restrict__ counts, int* __restrict__ offs,
                  int* __restrict__ rows, int* __restrict__ cnts)
{
    __shared__ int sbuf[1024];
    __shared__ int nbuf[1024];
    int dl = blockIdx.x;
    const int4* c4 = reinterpret_cast<const int4*>(counts + (size_t)dl * 65536);
    int* o = offs + (size_t)dl * OSTR;
    int* rw = rows + (size_t)dl * 65536;
    int t = threadIdx.x;
    int cv[64];
#pragma unroll 4
    for (int k4 = 0; k4 < 16; ++k4) {
        int4 v = c4[t * 16 + k4];
        cv[k4 * 4 + 0] = v.x; cv[k4 * 4 + 1] = v.y;
        cv[k4 * 4 + 2] = v.z; cv[k4 * 4 + 3] = v.w;
    }
    int s = 0, nz = 0;
#pragma unroll
    for (int k = 0; k < 64; ++k) { s += cv[k]; nz += (cv[k] > 0); }
    sbuf[t] = s;
    nbuf[t] = nz;
    __syncthreads();
    int val = s, nval = nz;
    for (int off = 1; off < 1024; off <<= 1) {
        int add  = (t >= off) ? sbuf[t - off] : 0;
        int nadd = (t >= off) ? nbuf[t - off] : 0;
        __syncthreads();
        val += add;
        nval += nadd;
        sbuf[t] = val;
        nbuf[t] = nval;
        __syncthreads();
    }
    int run  = val - s;
    int nrun = nval - nz;
    int base = t * 64;
    int4* o4 = reinterpret_cast<int4*>(o + base);
#pragma unroll 4
    for (int k4 = 0; k4 < 16; ++k4) {
        int4 ov;
        ov.x = run; run += cv[k4 * 4 + 0];
        ov.y = run; run += cv[k4 * 4 + 1];
        ov.z = run; run += cv[k4 * 4 + 2];
        ov.w = run; run += cv[k4 * 4 + 3];
        o4[k4] = ov;
#pragma unroll
        for (int q = 0; q < 4; ++q)
            if (cv[k4 * 4 + q] > 0) rw[nrun++] = base + k4 * 4 + q;
    }
    if (t == 1023) { o[65536] = val; cnts[dl] = nval; }
}

// ---------------------------------------------------------------------------
__global__ __launch_bounds__(256)
void fill_csr(const int* __restrict__ ei, const float* __restrict__ edot_f,
              const float* __restrict__ edot_b, const int* __restrict__ offs,
              int* __restrict__ cursor, int2* __restrict__ csr)
{
    int idx = blockIdx.x * 256 + threadIdx.x;       // < 2E
    int dir = idx >= E_EDGES;
    int ge = dir ? idx - E_EDGES : idx;
    int lv = ge >> 16;
    int dl = dir * 8 + lv;
    int i = dir ? ei[ge] : ei[E_EDGES + ge];
    int j = dir ? ei[E_EDGES + ge] : ei[ge];
    int pos = offs[(size_t)dl * OSTR + i] + atomicAdd(&cursor[(size_t)dl * 65536 + i], 1);
    int2 v;
    v.x = j;
    v.y = __float_as_int(dir ? edot_b[ge] : edot_f[ge]);
    csr[(size_t)dl * EL + pos] = v;
}

// ---------------------------------------------------------------------------
// qdot for all nodes; exact-f32 GRU for roots. Always writes h f32 + hi image
// for roots; lo image only when write_lo (dir 0).
__global__ __launch_bounds__(256)
void root_init(const float* __restrict__ hp, const int* __restrict__ flag,
               const float* __restrict__ Wi, const float* __restrict__ bi,
               const float* __restrict__ bh, const float* __restrict__ wa,
               float* __restrict__ h, unsigned char* __restrict__ h_hi,
               unsigned char* __restrict__ h_lo, int write_lo,
               float* __restrict__ qdot, float* __restrict__ hdot)
{
    int wv = threadIdx.x >> 6, lane = threadIdx.x & 63;
    int n = blockIdx.x * 4 + wv;
    int d = lane << 1;
    const float* hprow = hp + (size_t)n * 128;
    float2 hpv = *reinterpret_cast<const float2*>(hprow + d);
    float qd = wave_sum(hpv.x * wa[d] + hpv.y * wa[d + 1]);
    if (lane == 0) qdot[n] = qd;
    bool root = (flag[n] == 0);
    float hv[2] = {0.f, 0.f};
    if (root) {   // rare; exact f32 path
#pragma unroll
        for (int q = 0; q < 2; ++q) {
            int dd = d + q;
            float g0 = bi[dd], g1 = bi[dd + 128], g2 = bi[dd + 256];
            for (int k = 0; k < 128; ++k) {
                float a = hprow[k];
                g0 = fmaf(a, Wi[(size_t)dd * 128 + k], g0);
                g1 = fmaf(a, Wi[(size_t)(dd + 128) * 128 + k], g1);
                g2 = fmaf(a, Wi[(size_t)(dd + 256) * 128 + k], g2);
            }
            float rr = sigmoidf_(g0 + bh[dd]);
            float zz = sigmoidf_(g1 + bh[dd + 128]);
            float nn = tanhf(g2 + rr * bh[dd + 256]);
            hv[q] = (1.f - zz) * nn;            // hidden = 0 for roots
        }
        *reinterpret_cast<float2*>(h + (size_t)n * 128 + d) = make_float2(hv[0], hv[1]);
        u32 hb0 = bf_hi(hv[0]), hb1 = bf_hi(hv[1]);
        size_t off = (size_t)n * 256 + (size_t)d * 2;
        *reinterpret_cast<u32*>(h_hi + off) = hb0 | (hb1 << 16);
        if (write_lo) {
            u32 lb0 = bf_hi(hv[0] - bf_f(hb0)), lb1 = bf_hi(hv[1] - bf_f(hb1));
            *reinterpret_cast<u32*>(h_lo + off) = lb0 | (lb1 << 16);
        }
    }
    float hd = wave_sum(hv[0] * wa[128 + d] + hv[1] * wa[128 + d + 1]);
    if (lane == 0) hdot[n] = root ? hd : 0.f;
}

// ---------------------------------------------------------------------------
// Half-wave per target: softmax aggregation. V gathered from the bf16 h-image
// (256B/row, half the traffic of f32). Writes msg as bf16-hi image.
__global__ __launch_bounds__(256)
void attn_msg(const int* __restrict__ pcnt, const int* __restrict__ rows,
              const int* __restrict__ offs, const int2* __restrict__ csr,
              const float* __restrict__ qdot, const float* __restrict__ hdot,
              const unsigned char* __restrict__ h_img, unsigned char* __restrict__ msg_hi)
{
    int cnt = *pcnt;
    int l31 = threadIdx.x & 31;
    int hid = (blockIdx.x * 256 + threadIdx.x) >> 5;
    int nh = (gridDim.x * 256) >> 5;
    int d4 = l31 << 2;
    for (int r = hid; r < cnt; r += nh) {
        int i = rows[r];
        int o0 = offs[i], o1 = offs[i + 1];
        float qi = qdot[i];
        float den = 0.f;
        float4 acc = make_float4(0.f, 0.f, 0.f, 0.f);
        int2 je = csr[o0];
        for (int e = o0; e < o1; ++e) {
            int en = e + 1;
            int2 jn = (en < o1) ? csr[en] : je;   // one-ahead prefetch
            float ex = expf(qi + hdot[je.x] + __int_as_float(je.y));
            uint2 w = *reinterpret_cast<const uint2*>(
                h_img + (size_t)je.x * 256 + (size_t)d4 * 2);
            float v0 = __uint_as_float(w.x << 16);
            float v1 = __uint_as_float(w.x & 0xffff0000u);
            float v2 = __uint_as_float(w.y << 16);
            float v3 = __uint_as_float(w.y & 0xffff0000u);
            den += ex;
            acc.x = fmaf(ex, v0, acc.x);
            acc.y = fmaf(ex, v1, acc.y);
            acc.z = fmaf(ex, v2, acc.z);
            acc.w = fmaf(ex, v3, acc.w);
            je = jn;
        }
        float inv = 1.f / den;
        u32 h0 = bf_hi(acc.x * inv), h1 = bf_hi(acc.y * inv);
        u32 h2 = bf_hi(acc.z * inv), h3 = bf_hi(acc.w * inv);
        *reinterpret_cast<uint2*>(msg_hi + (size_t)r * 256 + (size_t)d4 * 2) =
            make_uint2(h0 | (h1 << 16), h2 | (h3 << 16));
    }
}

// ---------------------------------------------------------------------------
// Dual-phase GEMM + GRU. 64-row tile, 256 thr (4 waves), LDS exactly 80KB ->
// 2 blocks/CU. Phase A (t=0..3): msg_hi @ Wh_hi (single-term);
// Phase B (t=4..7): hp(hi+lo) @ Wi (r/z 2-term, n 3-term).
// Epilogue always writes h f32 + hi image; lo image only when write_lo.
__global__ __launch_bounds__(256, 2)
void gemm_gru(const unsigned char* __restrict__ msg_hi,
              const unsigned char* __restrict__ hp_hi, const unsigned char* __restrict__ hp_lo,
              const u16* __restrict__ Whhi,
              const u16* __restrict__ Wihi, const u16* __restrict__ Wilo,
              const int* __restrict__ pcnt, const int* __restrict__ rows,
              const float* __restrict__ bi, const float* __restrict__ bh,
              const float* __restrict__ wa,
              float* __restrict__ h, unsigned char* __restrict__ h_hi,
              unsigned char* __restrict__ h_lo, int write_lo,
              float* __restrict__ hdot)
{
    __shared__ __align__(16) unsigned char smem[16384 + 65536];  // As 2x8K | Bs 2x32K
    unsigned char* As = smem;
    unsigned char* Bs = smem + 16384;

    const int tid = threadIdx.x;
    const int cnt = *pcnt;
    const int row0 = blockIdx.x * 64;
    if (row0 >= cnt) return;

    const int lane = tid & 63, wv = tid >> 6;
    const int q = wv;                 // col slice
    const int l31 = lane & 31, l5 = lane >> 5;

    // A-source per-lane offsets (swizzle folded into source address)
    const int rwA = wv * 16 + (lane >> 2);                 // 0..63
    const int slA = ((lane & 3) << 4) ^ ((rwA & 3) << 4);
    int garA = row0 + rwA;
    const size_t baseA0 = (size_t)garA * 256 + slA;        // dense msg rows
    int rowA1 = rows[garA < cnt ? garA : 0];
    const size_t baseA1 = (size_t)rowA1 * 256 + slA;       // gathered hp rows
    // B-source offsets: hi 6 DMAs (384 rows), lo 2 DMAs (128 rows)
    size_t bsrc[6];
#pragma unroll
    for (int k = 0; k < 6; ++k) {
        int rwB = wv * 96 + k * 16 + (lane >> 2);
        bsrc[k] = (size_t)rwB * 256 + (((lane & 3) << 4) ^ ((rwB & 3) << 4));
    }
    size_t lsrc[2];
#pragma unroll
    for (int k = 0; k < 2; ++k) {
        int rwL = wv * 32 + k * 16 + (lane >> 2);
        lsrc[k] = (size_t)rwL * 256 + (((lane & 3) << 4) ^ ((rwL & 3) << 4));
    }

    f32x16 acc[2][3];
#pragma unroll
    for (int mt = 0; mt < 2; ++mt)
#pragma unroll
        for (int g = 0; g < 3; ++g) acc[mt][g] = (f32x16)0.0f;
    f32x16 ghn[2];

    auto STAGE = [&](int tt) {
        int b = tt & 1;
        size_t ko = (size_t)(tt & 3) * 64;
        unsigned char* Bd = Bs + b * 32768;
        if (tt < 4) {      // phase A: msg hi + Wh hi (7 DMA/wave)
            gload_lds16(msg_hi + baseA0 + ko, As + b * 8192 + wv * 1024);
#pragma unroll
            for (int k = 0; k < 6; ++k)
                gload_lds16((const unsigned char*)Whhi + bsrc[k] + ko, Bd + (wv * 6 + k) * 1024);
        } else {           // phase B: hp hi+lo + Wi hi+lo (10 DMA/wave)
            gload_lds16(hp_hi + baseA1 + ko, As + b * 8192 + wv * 1024);
            gload_lds16(hp_lo + baseA1 + ko, As + b * 8192 + 4096 + wv * 1024);
#pragma unroll
            for (int k = 0; k < 6; ++k)
                gload_lds16((const unsigned char*)Wihi + bsrc[k] + ko, Bd + (wv * 6 + k) * 1024);
#pragma unroll
            for (int k = 0; k < 2; ++k)
                gload_lds16((const unsigned char*)Wilo + lsrc[k] + ko, Bd + 24576 + (wv * 2 + k) * 1024);
        }
    };

    STAGE(0);
    for (int t = 0; t < 8; ++t) {
        if (t < 7) STAGE(t + 1);
        __builtin_amdgcn_sched_barrier(0);
        if (t < 3)      asm volatile("s_waitcnt vmcnt(7)");    // next = phase-A tile
        else if (t < 7) asm volatile("s_waitcnt vmcnt(10)");   // next = phase-B tile
        else            asm volatile("s_waitcnt vmcnt(0)");
        __builtin_amdgcn_s_barrier();
        __builtin_amdgcn_sched_barrier(0);

        const unsigned char* Ab = As + (t & 1) * 8192;
        const unsigned char* Bb = Bs + (t & 1) * 32768;
#pragma unroll
        for (int kh = 0; kh < 2; ++kh) {
            short8 b0 = *reinterpret_cast<const short8*>(
                Bb + swz(q * 32 + l31, kh * 32 + l5 * 16));
            short8 b1 = *reinterpret_cast<const short8*>(
                Bb + swz(q * 32 + 128 + l31, kh * 32 + l5 * 16));
            short8 b2 = *reinterpret_cast<const short8*>(
                Bb + swz(q * 32 + 256 + l31, kh * 32 + l5 * 16));
            short8 ah[2];
#pragma unroll
            for (int mt = 0; mt < 2; ++mt)
                ah[mt] = *reinterpret_cast<const short8*>(
                    Ab + swz(mt * 32 + l31, kh * 32 + l5 * 16));
            if (t < 4) {   // phase A: single-term
#pragma unroll
                for (int mt = 0; mt < 2; ++mt) {
                    acc[mt][0] = __builtin_amdgcn_mfma_f32_32x32x16_bf16(ah[mt], b0, acc[mt][0], 0, 0, 0);
                    acc[mt][1] = __builtin_amdgcn_mfma_f32_32x32x16_bf16(ah[mt], b1, acc[mt][1], 0, 0, 0);
                    acc[mt][2] = __builtin_amdgcn_mfma_f32_32x32x16_bf16(ah[mt], b2, acc[mt][2], 0, 0, 0);
                }
            } else {       // phase B: r/z 2-term, n 3-term
                short8 bl2 = *reinterpret_cast<const short8*>(
                    Bb + 24576 + swz(q * 32 + l31, kh * 32 + l5 * 16));
                short8 al[2];
#pragma unroll
                for (int mt = 0; mt < 2; ++mt)
                    al[mt] = *reinterpret_cast<const short8*>(
                        Ab + 4096 + swz(mt * 32 + l31, kh * 32 + l5 * 16));
#pragma unroll
                for (int mt = 0; mt < 2; ++mt) {
                    acc[mt][0] = __builtin_amdgcn_mfma_f32_32x32x16_bf16(ah[mt], b0, acc[mt][0], 0, 0, 0);
                    acc[mt][0] = __builtin_amdgcn_mfma_f32_32x32x16_bf16(al[mt], b0, acc[mt][0], 0, 0, 0);
                    acc[mt][1] = __builtin_amdgcn_mfma_f32_32x32x16_bf16(ah[mt], b1, acc[mt][1], 0, 0, 0);
                    acc[mt][1] = __builtin_amdgcn_mfma_f32_32x32x16_bf16(al[mt], b1, acc[mt][1], 0, 0, 0);
                    acc[mt][2] = __builtin_amdgcn_mfma_f32_32x32x16_bf16(ah[mt], b2, acc[mt][2], 0, 0, 0);
                    acc[mt][2] = __builtin_amdgcn_mfma_f32_32x32x16_bf16(ah[mt], bl2, acc[mt][2], 0, 0, 0);
                    acc[mt][2] = __builtin_amdgcn_mfma_f32_32x32x16_bf16(al[mt], b2, acc[mt][2], 0, 0, 0);
                }
            }
        }
        if (t == 3) {                        // end of phase A: stash gh_n
            ghn[0] = acc[0][2];
            ghn[1] = acc[1][2];
            acc[0][2] = (f32x16)0.0f;
            acc[1][2] = (f32x16)0.0f;
        }
        __builtin_amdgcn_s_barrier();        // reads done before buf reuse
        __builtin_amdgcn_sched_barrier(0);
    }

    // ---- epilogue (red aliases Bs — dead after the loop)
    __syncthreads();
    float* red = (float*)Bs;                  // [64][4]
    const int d = q * 32 + l31;
    const float wa2d = wa[128 + d];
    const float bi0 = bi[d], bi1 = bi[d + 128], bi2 = bi[d + 256];
    const float bh0 = bh[d], bh1 = bh[d + 128], bh2 = bh[d + 256];

#pragma unroll
    for (int mt = 0; mt < 2; ++mt)
#pragma unroll
        for (int rg = 0; rg < 16; ++rg) {
            int rl = mt * 32 + (rg & 3) + ((rg >> 2) << 3) + (l5 << 2);
            int gr = row0 + rl;
            bool ok = gr < cnt;
            int n = rows[ok ? gr : 0];
            float mval = bf_f(*reinterpret_cast<const u16*>(
                msg_hi + (size_t)gr * 256 + (size_t)d * 2));
            float rr = sigmoidf_(acc[mt][0][rg] + bi0 + bh0);
            float zz = sigmoidf_(acc[mt][1][rg] + bi1 + bh1);
            float nn = tanhf(acc[mt][2][rg] + bi2 + rr * (ghn[mt][rg] + bh2));
            float hv = (1.f - zz) * nn + zz * mval;    // hidden = msg
            if (ok) {
                h[(size_t)n * 128 + d] = hv;
                u32 hb = bf_hi(hv);
                *reinterpret_cast<u16*>(h_hi + (size_t)n * 256 + (size_t)d * 2) = (u16)hb;
                if (write_lo)
                    *reinterpret_cast<u16*>(h_lo + (size_t)n * 256 + (size_t)d * 2) =
                        (u16)bf_hi(hv - bf_f(hb));
            }
            float pd = hv * wa2d;
#pragma unroll
            for (int o = 1; o < 32; o <<= 1) pd += __shfl_xor(pd, o, 64);
            if (l31 == 0) red[rl * 4 + q] = pd;
        }
    __syncthreads();
    if (tid < 64 && row0 + tid < cnt) {
        int n = rows[row0 + tid];
        hdot[n] = red[tid * 4] + red[tid * 4 + 1] + red[tid * 4 + 2] + red[tid * 4 + 3];
    }
}

// ---------------------------------------------------------------------------
__global__ __launch_bounds__(256)
void relu_kernel(const float* __restrict__ h, float* __restrict__ out)
{
    int idx = (blockIdx.x * 256 + threadIdx.x) * 4;
    float4 v = *reinterpret_cast<const float4*>(h + idx);
    v.x = fmaxf(v.x, 0.f); v.y = fmaxf(v.y, 0.f);
    v.z = fmaxf(v.z, 0.f); v.w = fmaxf(v.w, 0.f);
    *reinterpret_cast<float4*>(out + idx) = v;
}

// ---------------------------------------------------------------------------
extern "C" void kernel_launch(void* const* d_in, const int* in_sizes, int n_in,
                              void* d_out, int out_size, void* d_ws, size_t ws_size,
                              hipStream_t stream)
{
    (void)in_sizes; (void)n_in; (void)out_size; (void)ws_size;

    const float* x    = (const float*)d_in[0];
    const int*   ei   = (const int*)d_in[1];
    const float* ea   = (const float*)d_in[2];
    const float* We_f = (const float*)d_in[4];
    const float* be_f = (const float*)d_in[5];
    const float* Wa_f = (const float*)d_in[6];
    const float* ba_f = (const float*)d_in[7];
    const float* Wi_f = (const float*)d_in[8];
    const float* Wh_f = (const float*)d_in[9];
    const float* bi_f = (const float*)d_in[10];
    const float* bh_f = (const float*)d_in[11];
    const float* We_b = (const float*)d_in[12];
    const float* be_b = (const float*)d_in[13];
    const float* Wa_b = (const float*)d_in[14];
    const float* ba_b = (const float*)d_in[15];
    const float* Wi_b = (const float*)d_in[16];
    const float* Wh_b = (const float*)d_in[17];
    const float* bi_b = (const float*)d_in[18];
    const float* bh_b = (const float*)d_in[19];
    float* out = (float*)d_out;

    char* p = (char*)d_ws;
    auto carve = [&](size_t bytes) -> char* {
        char* r = p;
        p += (bytes + 255) & ~(size_t)255;
        return r;
    };
    // ---- zeroed region (contiguous, one memset per launch) ----
    int*   counts  = (int*)carve((size_t)16 * 65536 * 4);
    int*   cursor  = (int*)carve((size_t)16 * 65536 * 4);
    int*   flag_f  = (int*)carve((size_t)N_NODES * 4);
    int*   flag_b  = (int*)carve((size_t)N_NODES * 4);
    float* h_fwd   = (float*)carve((size_t)N_NODES * D * 4);   // must start 0
    float* h_cur   = (float*)carve((size_t)N_NODES * D * 4);   // must start 0
    unsigned char* hf_hi = (unsigned char*)carve((size_t)N_NODES * 256); // h_fwd hi image
    unsigned char* hc_hi = (unsigned char*)carve((size_t)N_NODES * 256); // h_cur hi image
    size_t zbytes  = (size_t)((char*)hc_hi - (char*)counts) + (size_t)N_NODES * 256;
    // ---- rest (fully written each launch before use) ----
    unsigned char* hf_lo = (unsigned char*)carve((size_t)N_NODES * 256);
    int*   cnts    = (int*)carve(256);
    u16*   Whi4    = (u16*)carve((size_t)4 * 49152 * 2);   // WiF,WhF,WiB,WhB hi
    u16*   Wlo4    = (u16*)carve((size_t)4 * 16384 * 2);   // n-gate rows lo
    unsigned char* x_hi  = (unsigned char*)carve((size_t)N_NODES * 256);
    unsigned char* x_lo  = (unsigned char*)carve((size_t)N_NODES * 256);
    unsigned char* msg_hi= (unsigned char*)carve((size_t)N_NODES * 256);
    float* u_f     = (float*)carve((size_t)D * 4);
    float* u_b     = (float*)carve((size_t)D * 4);
    float* cst     = (float*)carve(16);
    float* edot_f  = (float*)carve((size_t)E_EDGES * 4);
    float* edot_b  = (float*)carve((size_t)E_EDGES * 4);
    int*   offs    = (int*)carve((size_t)16 * OSTR * 4);
    int2*  csr     = (int2*)carve((size_t)16 * EL * 8);
    int*   rows    = (int*)carve((size_t)16 * 65536 * 4);
    float* qdot    = (float*)carve((size_t)N_NODES * 4);
    float* hdot    = (float*)carve((size_t)N_NODES * 4);

    hipMemsetAsync(counts, 0, zbytes, stream);
    prep_kernel<<<1, 256, 0, stream>>>(We_f, Wa_f, be_f, ba_f, We_b, Wa_b, be_b, ba_b,
                                       u_f, u_b, cst);
    convert_w<<<dim3(192, 4), 256, 0, stream>>>(Wi_f, Wh_f, Wi_b, Wh_b, Whi4, Wlo4);
    convert_x<<<16384, 256, 0, stream>>>(x, x_hi, x_lo);
    edot_count<<<E_EDGES / 32, 256, 0, stream>>>(ea, u_f, u_b, cst, ei,
                                                 edot_f, edot_b, counts, flag_f, flag_b);
    scan_compact<<<16, 1024, 0, stream>>>(counts, offs, rows, cnts);
    fill_csr<<<2 * E_EDGES / 256, 256, 0, stream>>>(ei, edot_f, edot_b, offs, cursor, csr);

    for (int dir = 0; dir < 2; ++dir) {
        const float* hp   = dir == 0 ? x : h_fwd;
        float*       h    = dir == 0 ? h_fwd : h_cur;
        const unsigned char* hp_hi = dir == 0 ? x_hi : hf_hi;
        const unsigned char* hp_lo = dir == 0 ? x_lo : hf_lo;
        unsigned char* h_hi = dir == 0 ? hf_hi : hc_hi;   // current-state hi image
        unsigned char* h_lo = hf_lo;                       // lo only maintained for dir 0
        int write_lo = (dir == 0);
        const u16* Wihi = Whi4 + (size_t)(dir * 2) * 49152;
        const u16* Whhi = Whi4 + (size_t)(dir * 2 + 1) * 49152;
        const u16* Wilo = Wlo4 + (size_t)(dir * 2) * 16384;
        const float* Wi   = dir == 0 ? Wi_f : Wi_b;
        const float* bi   = dir == 0 ? bi_f : bi_b;
        const float* bh   = dir == 0 ? bh_f : bh_b;
        const float* wa   = dir == 0 ? Wa_f : Wa_b;
        const int*   flag = dir == 0 ? flag_f : flag_b;

        root_init<<<N_NODES / 4, 256, 0, stream>>>(hp, flag, Wi, bi, bh, wa,
                                                   h, h_hi, h_lo, write_lo, qdot, hdot);

        for (int t = 0; t < LVLS; ++t) {
            int lv = dir == 0 ? t : (LVLS - 1 - t);
            int dl = dir * LVLS + lv;
            attn_msg<<<2048, 256, 0, stream>>>(
                cnts + dl, rows + (size_t)dl * 65536, offs + (size_t)dl * OSTR,
                csr + (size_t)dl * EL, qdot, hdot, h_hi, msg_hi);
            gemm_gru<<<1024, 256, 0, stream>>>(
                msg_hi, hp_hi, hp_lo, Whhi, Wihi, Wilo,
                cnts + dl, rows + (size_t)dl * 65536,
                bi, bh, wa, h, h_hi, h_lo, write_lo, hdot);
        }
    }
    relu_kernel<<<(N_NODES * D) / 1024, 256, 0, stream>>>(h_cur, out);
}